// Round 5
// baseline (3985.963 us; speedup 1.0000x reference)
//
#include <hip/hip_runtime.h>
#include <math.h>

// Sinkhorn loss, B=8, S=2048, P=1024, D=2, eps=0.01, 50 iters.
// PERSISTENT-KERNEL v5 — 16 waves/CU + spill-free two-pass LSE.
// R3/R4 lesson (counters): VALU-busy time constant ~330us while duration
// 1918/2462us => latency-bound at 1-2 waves/SIMD; R4's u[128] spilled
// (VGPR 124, WRITE_SIZE 7->39MB). v5: 1024thr/block (4 waves/SIMD, LDS
// still 1 block/CU so spin-barrier geometry is safe), and the LSE does
// pass1 max-only + pass2 recompute-into-exp2 (no u[] storage => ~60 VGPR,
// no spills, launch_bounds(1024,4) caps at 128).
// Base-2 scaled potentials: F2 = f/(eps*ln2), G2 = g/(eps*ln2), K = 100*log2(e)
//   f elem: u = 2K*x.y + (G2[p] - K*y2[p]);  F2 = (K*x2 - log2 S) - LSE2(u)
//   g elem: u = 2K*x.y + (F2[s] - K*x2[s]);  G2 = (K*y2 + logb2) - LSE2(u)

#define BB 8
#define SS 2048
#define PP 1024
#define NEG_INF -1e9f
#define LOG2S 11.0f
#define ITERS 50
#define K2E 144.269504088896f   /* 100*log2(e) */
#define TWOK 288.539008177792f  /* 200*log2(e) */
#define NBLK 256
#define BLK_PER_BATCH 32

__device__ __forceinline__ float fexp2(float x) {
  return __builtin_amdgcn_exp2f(x);
}
__device__ __forceinline__ float flog2(float x) {
  return __builtin_amdgcn_logf(x);
}

// agent-scope coherent (cache-bypassing) accessors for cross-XCD data
__device__ __forceinline__ float coh_load(const float* p) {
  return __hip_atomic_load((float*)p, __ATOMIC_RELAXED, __HIP_MEMORY_SCOPE_AGENT);
}
__device__ __forceinline__ void coh_store(float* p, float v) {
  __hip_atomic_store(p, v, __ATOMIC_RELAXED, __HIP_MEMORY_SCOPE_AGENT);
}

// 32-block per-batch barrier; target is monotonic (32 * phase_number).
__device__ __forceinline__ void batch_barrier(int* cnt, int target) {
  __syncthreads();  // all waves drain their stores (vmcnt0) before arrival
  if (threadIdx.x == 0) {
    __hip_atomic_fetch_add(cnt, 1, __ATOMIC_RELEASE, __HIP_MEMORY_SCOPE_AGENT);
    while (__hip_atomic_load(cnt, __ATOMIC_ACQUIRE, __HIP_MEMORY_SCOPE_AGENT) <
           target)
      __builtin_amdgcn_s_sleep(2);
  }
  __syncthreads();
  __builtin_amdgcn_fence(__ATOMIC_ACQUIRE, "agent");
}

// ws layout (bytes):
//   G2    : [0,      32768)   B*P float
//   F2    : [32768,  98304)   B*S float
//   logb2 : [98304, 131072)   B*P float
//   cnt   : [131072, 135168)  8 batch counters, stride 32 ints (128 B)

__global__ __launch_bounds__(1024) void setup_kernel(
    const int* __restrict__ labels, float* __restrict__ G2,
    float* __restrict__ logb2, int* __restrict__ cnt,
    float* __restrict__ out) {
  __shared__ int c[PP];
  int b = blockIdx.x;
  int t = threadIdx.x;  // 1024 threads
  c[t] = 0;
  __syncthreads();
  atomicAdd(&c[labels[b * SS + t] & (PP - 1)], 1);
  atomicAdd(&c[labels[b * SS + PP + t] & (PP - 1)], 1);
  __syncthreads();
  int cc = c[t];
  logb2[b * PP + t] = (cc > 0) ? (flog2((float)cc) - LOG2S) : NEG_INF;
  G2[b * PP + t] = 0.0f;
  if (t == 0) {
    cnt[b << 5] = 0;
    if (b == 0) out[0] = 0.0f;
  }
}

__global__ __launch_bounds__(1024, 4) void sinkhorn_persist(
    const float* __restrict__ preds, const float* __restrict__ pos,
    const float* __restrict__ logb2, float* __restrict__ F2g,
    float* __restrict__ G2g, int* __restrict__ cnt, float* __restrict__ out) {
  __shared__ float4 shf[1032];  // (y0, y1, qy = G2 - K*y2, pad), +16B pad /128
  __shared__ float4 shg[2064];  // (x0, x1, qx = F2 - K*x2, pad), +16B pad /128
  __shared__ float spart;
  const int t = threadIdx.x;    // 1024 threads, 16 waves
  const int blk = blockIdx.x;   // 256 blocks = 1/CU
  const int bb = blk >> 5;      // 32 blocks per batch
  int* mycnt = cnt + (bb << 5);
  const float2* pos2 = (const float2*)pos;
  const float2* preds2 = (const float2*)preds;
  float* G2b = G2g + (bb << 10);
  float* F2b = F2g + (bb << 11);

  // ---- persistent init: x/y constants into LDS + K-scaled norms in regs
  float yr2, xr2[2];
  {
    float2 y = pos2[(bb << 10) + t];
    yr2 = y.x * y.x + y.y * y.y;
    shf[t + (t >> 7)] = make_float4(y.x, y.y, 0.0f, 0.0f);
  }
#pragma unroll
  for (int k = 0; k < 2; ++k) {
    int e = t + (k << 10);
    float2 x = preds2[(bb << 11) + e];
    xr2[k] = x.x * x.x + x.y * x.y;
    shg[e + (e >> 7)] = make_float4(x.x, x.y, 0.0f, 0.0f);
  }

  const int w = t >> 6, lane = t & 63;
  // f-phase: wave w owns 4 rows [blk*64 + w*4, +4); lane covers 16 cols
  const int frowb = (blk << 6) + (w << 2);
  float fk0[4], fk1[4], fc0[4];
#pragma unroll
  for (int r = 0; r < 4; ++r) {
    float2 fx = preds2[frowb + r];  // wave-uniform broadcast load
    fk0[r] = TWOK * fx.x;
    fk1[r] = TWOK * fx.y;
    fc0[r] = fmaf(K2E, fx.x * fx.x + fx.y * fx.y, -LOG2S);
  }
  // g-phase: wave w owns 2 cols [blk*32 + w*2, +2); lane covers 32 rows
  const int gcolb = (blk << 5) + (w << 1);
  float gk0[2], gk1[2], gc0[2];
#pragma unroll
  for (int c = 0; c < 2; ++c) {
    float2 gy = pos2[gcolb + c];
    gk0[c] = TWOK * gy.x;
    gk1[c] = TWOK * gy.y;
    gc0[c] = fmaf(K2E, gy.x * gy.x + gy.y * gy.y, logb2[gcolb + c]);
  }

  int target = 0;

  for (int it = 0; it < ITERS; ++it) {
    // ---- stage qy = G2 - K*y2 (4KB coherent reads; same-thread LDS slots)
    shf[t + (t >> 7)].z = fmaf(-K2E, yr2, coh_load(&G2b[t]));
    __syncthreads();
    // ---- f-compute: pass1 max (no storage), pass2 recompute + exp2
    {
      float m[4], s[4];
#pragma unroll
      for (int r = 0; r < 4; ++r) m[r] = -3.4e38f;
#pragma unroll
      for (int i = 0; i < 16; ++i) {
        int e = (i << 6) + lane;  // consecutive-lane: conflict-free
        float4 a = shf[e + (e >> 7)];
#pragma unroll
        for (int r = 0; r < 4; ++r)
          m[r] = fmaxf(m[r], fmaf(fk0[r], a.x, fmaf(fk1[r], a.y, a.z)));
      }
#pragma unroll
      for (int off = 1; off <= 32; off <<= 1)
#pragma unroll
        for (int r = 0; r < 4; ++r) m[r] = fmaxf(m[r], __shfl_xor(m[r], off, 64));
#pragma unroll
      for (int r = 0; r < 4; ++r) s[r] = 0.0f;
#pragma unroll
      for (int i = 0; i < 16; ++i) {
        int e = (i << 6) + lane;
        float4 a = shf[e + (e >> 7)];
#pragma unroll
        for (int r = 0; r < 4; ++r)
          s[r] += fexp2(fmaf(fk0[r], a.x, fmaf(fk1[r], a.y, a.z - m[r])));
      }
#pragma unroll
      for (int off = 1; off <= 32; off <<= 1)
#pragma unroll
        for (int r = 0; r < 4; ++r) s[r] += __shfl_xor(s[r], off, 64);
      if (lane == 0) {
#pragma unroll
        for (int r = 0; r < 4; ++r)
          coh_store(&F2g[frowb + r], fc0[r] - m[r] - flog2(s[r]));
      }
    }
    target += BLK_PER_BATCH;
    batch_barrier(mycnt, target);

    // ---- stage qx = F2 - K*x2 (8KB coherent reads)
#pragma unroll
    for (int k = 0; k < 2; ++k) {
      int e = t + (k << 10);
      shg[e + (e >> 7)].z = fmaf(-K2E, xr2[k], coh_load(&F2b[e]));
    }
    __syncthreads();
    // ---- g-compute: pass1 max, pass2 recompute + exp2
    {
      float m[2], s[2];
#pragma unroll
      for (int c = 0; c < 2; ++c) m[c] = -3.4e38f;
#pragma unroll
      for (int j = 0; j < 32; ++j) {
        int e = (j << 6) + lane;
        float4 a = shg[e + (e >> 7)];
#pragma unroll
        for (int c = 0; c < 2; ++c)
          m[c] = fmaxf(m[c], fmaf(gk0[c], a.x, fmaf(gk1[c], a.y, a.z)));
      }
#pragma unroll
      for (int off = 1; off <= 32; off <<= 1)
#pragma unroll
        for (int c = 0; c < 2; ++c) m[c] = fmaxf(m[c], __shfl_xor(m[c], off, 64));
#pragma unroll
      for (int c = 0; c < 2; ++c) s[c] = 0.0f;
#pragma unroll
      for (int j = 0; j < 32; ++j) {
        int e = (j << 6) + lane;
        float4 a = shg[e + (e >> 7)];
#pragma unroll
        for (int c = 0; c < 2; ++c)
          s[c] += fexp2(fmaf(gk0[c], a.x, fmaf(gk1[c], a.y, a.z - m[c])));
      }
#pragma unroll
      for (int off = 1; off <= 32; off <<= 1)
#pragma unroll
        for (int c = 0; c < 2; ++c) s[c] += __shfl_xor(s[c], off, 64);
      if (lane == 0) {
#pragma unroll
        for (int c = 0; c < 2; ++c)
          coh_store(&G2g[gcolb + c], gc0[c] - m[c] - flog2(s[c]));
      }
    }
    target += BLK_PER_BATCH;
    batch_barrier(mycnt, target);
  }

  // ---- fused final: restage qy with final G2, rowsum over own 64 rows
  if (t == 0) spart = 0.0f;
  shf[t + (t >> 7)].z = fmaf(-K2E, yr2, coh_load(&G2b[t]));
  __syncthreads();
  float acc = 0.0f;
#pragma unroll
  for (int rr = 0; rr < 4; ++rr) {
    int row = frowb + rr;
    float2 x = preds2[row];
    float x2 = x.x * x.x + x.y * x.y;
    float qx = fmaf(-K2E, x2, coh_load(&F2g[row]));
#pragma unroll
    for (int i = 0; i < 16; ++i) {
      int p = (i << 6) + lane;
      float4 a = shf[p + (p >> 7)];
      float y2 = fmaf(a.x, a.x, a.y * a.y);
      float tt = fmaf(x.y, a.y, x.x * a.x);
      float c = fmaxf(x2 + y2 - 2.0f * tt, 0.0f);  // clamped cost
      float v2 = fmaf(TWOK, tt, a.z + qx);         // -K*C' + F2 + G2 (base-2)
      acc = fmaf(fexp2(v2), c, acc);               // c==0 kills C'<0 case
    }
  }
#pragma unroll
  for (int off = 32; off; off >>= 1) acc += __shfl_xor(acc, off, 64);
  if (lane == 0) atomicAdd(&spart, acc);
  __syncthreads();
  if (t == 0) atomicAdd(out, spart * (1.0f / (float)BB));
}

extern "C" void kernel_launch(void* const* d_in, const int* in_sizes, int n_in,
                              void* d_out, int out_size, void* d_ws,
                              size_t ws_size, hipStream_t stream) {
  const float* preds = (const float*)d_in[0];  // [B,S,2]
  const int* labels = (const int*)d_in[1];     // [B,S]
  const float* pos = (const float*)d_in[2];    // [B,P,2]
  float* out = (float*)d_out;
  char* ws = (char*)d_ws;
  float* G2 = (float*)(ws);
  float* F2 = (float*)(ws + 32768);
  float* logb2 = (float*)(ws + 98304);
  int* cnt = (int*)(ws + 131072);

  hipLaunchKernelGGL(setup_kernel, dim3(BB), dim3(1024), 0, stream, labels, G2,
                     logb2, cnt, out);
  hipLaunchKernelGGL(sinkhorn_persist, dim3(NBLK), dim3(1024), 0, stream,
                     preds, pos, logb2, F2, G2, cnt, out);
}

// Round 6
// 779.436 us; speedup vs baseline: 5.1139x; 5.1139x over previous
//
#include <hip/hip_runtime.h>
#include <math.h>

// Sinkhorn loss, B=8, S=2048, P=1024, D=2, eps=0.01, 50 iters.
// PERSISTENT-KERNEL v6 — spill-free online LSE + relaxed barrier.
// Counter evidence R3->R5: WRITE_SIZE 7->39->213MB tracks scratch spills;
// agent-scope RELEASE(fetch_add)/ACQUIRE(per-poll!) emit L2 writeback/inv
// on gfx950, flushing dirty (spilled) L2 100x per block => barrier cost
// scales with spills. Also LDS traffic = waves x tile x passes (R5 doubled
// both). v6: (a) online chunked LSE, no u[] storage, no 2nd LDS pass, ~110
// VGPR => zero scratch; (b) fully RELAXED barrier (sc0/sc1 write-through
// stores + vmcnt drain at __syncthreads make release/acquire redundant for
// data that only moves via agent-scope ops); (c) 256 blk x 512 thr = 1/CU,
// 8 f-rows / 4 g-cols per wave, one 16B LDS read feeds 8 rows in regs.
// Base-2 scaled potentials: F2 = f/(eps*ln2), G2 = g/(eps*ln2), K = 100*log2(e)
//   f elem: u = 2K*x.y + (G2[p] - K*y2[p]);  F2 = (K*x2 - log2 S) - LSE2(u)
//   g elem: u = 2K*x.y + (F2[s] - K*x2[s]);  G2 = (K*y2 + logb2) - LSE2(u)

#define BB 8
#define SS 2048
#define PP 1024
#define NEG_INF -1e9f
#define LOG2S 11.0f
#define ITERS 50
#define K2E 144.269504088896f   /* 100*log2(e) */
#define TWOK 288.539008177792f  /* 200*log2(e) */
#define NBLK 256
#define BLK_PER_BATCH 32

__device__ __forceinline__ float fexp2(float x) {
  return __builtin_amdgcn_exp2f(x);
}
__device__ __forceinline__ float flog2(float x) {
  return __builtin_amdgcn_logf(x);
}

// agent-scope coherent (cache-bypassing) accessors for cross-XCD data.
// RELAXED only: sc0/sc1 ops read/write the coherence point directly; no
// release/acquire => no wbl2/inv instructions in the hot loop.
__device__ __forceinline__ float coh_load(const float* p) {
  return __hip_atomic_load((float*)p, __ATOMIC_RELAXED, __HIP_MEMORY_SCOPE_AGENT);
}
__device__ __forceinline__ void coh_store(float* p, float v) {
  __hip_atomic_store(p, v, __ATOMIC_RELAXED, __HIP_MEMORY_SCOPE_AGENT);
}

// 32-block per-batch barrier; target is monotonic (32 * phase_number).
// __syncthreads() drains vmcnt (all sc-stores at coherence point) before
// arrival; everything RELAXED, compiler-only fences.
__device__ __forceinline__ void batch_barrier(int* cnt, int target) {
  __syncthreads();
  asm volatile("" ::: "memory");
  if (threadIdx.x == 0) {
    __hip_atomic_fetch_add(cnt, 1, __ATOMIC_RELAXED, __HIP_MEMORY_SCOPE_AGENT);
    while (__hip_atomic_load(cnt, __ATOMIC_RELAXED, __HIP_MEMORY_SCOPE_AGENT) <
           target)
      __builtin_amdgcn_s_sleep(2);
  }
  asm volatile("" ::: "memory");
  __syncthreads();
}

// ws layout (bytes):
//   G2    : [0,      32768)   B*P float
//   F2    : [32768,  98304)   B*S float
//   logb2 : [98304, 131072)   B*P float
//   cnt   : [131072, 135168)  8 batch counters, stride 32 ints (128 B)

__global__ __launch_bounds__(1024) void setup_kernel(
    const int* __restrict__ labels, float* __restrict__ G2,
    float* __restrict__ logb2, int* __restrict__ cnt,
    float* __restrict__ out) {
  __shared__ int c[PP];
  int b = blockIdx.x;
  int t = threadIdx.x;  // 1024 threads
  c[t] = 0;
  __syncthreads();
  atomicAdd(&c[labels[b * SS + t] & (PP - 1)], 1);
  atomicAdd(&c[labels[b * SS + PP + t] & (PP - 1)], 1);
  __syncthreads();
  int cc = c[t];
  logb2[b * PP + t] = (cc > 0) ? (flog2((float)cc) - LOG2S) : NEG_INF;
  G2[b * PP + t] = 0.0f;
  if (t == 0) {
    cnt[b << 5] = 0;
    if (b == 0) out[0] = 0.0f;
  }
}

__global__ __launch_bounds__(512, 2) void sinkhorn_persist(
    const float* __restrict__ preds, const float* __restrict__ pos,
    const float* __restrict__ logb2, float* __restrict__ F2g,
    float* __restrict__ G2g, int* __restrict__ cnt, float* __restrict__ out) {
  __shared__ float4 shf[1032];  // (y0, y1, qy = G2 - K*y2, pad), +16B pad /128
  __shared__ float4 shg[2064];  // (x0, x1, qx = F2 - K*x2, pad), +16B pad /128
  __shared__ float spart;
  const int t = threadIdx.x;    // 512 threads, 8 waves
  const int blk = blockIdx.x;   // 256 blocks = 1/CU exactly
  const int bb = blk >> 5;      // 32 blocks per batch
  int* mycnt = cnt + (bb << 5);
  const float2* pos2 = (const float2*)pos;
  const float2* preds2 = (const float2*)preds;
  float* G2b = G2g + (bb << 10);
  float* F2b = F2g + (bb << 11);

  // ---- persistent init: x/y constants into LDS + K-scaled norms in regs
  float yr2[2], xr2[4];
#pragma unroll
  for (int k = 0; k < 2; ++k) {
    int e = t + (k << 9);
    float2 y = pos2[(bb << 10) + e];
    yr2[k] = y.x * y.x + y.y * y.y;
    shf[e + (e >> 7)] = make_float4(y.x, y.y, 0.0f, 0.0f);
  }
#pragma unroll
  for (int k = 0; k < 4; ++k) {
    int e = t + (k << 9);
    float2 x = preds2[(bb << 11) + e];
    xr2[k] = x.x * x.x + x.y * x.y;
    shg[e + (e >> 7)] = make_float4(x.x, x.y, 0.0f, 0.0f);
  }

  const int w = t >> 6, lane = t & 63;
  // f-phase: wave w owns 8 rows [blk*64 + w*8, +8); lane scans 16 cols
  const int frowb = (blk << 6) + (w << 3);
  float fk0[8], fk1[8], fc0[8];
#pragma unroll
  for (int r = 0; r < 8; ++r) {
    float2 fx = preds2[frowb + r];  // wave-uniform broadcast load
    fk0[r] = TWOK * fx.x;
    fk1[r] = TWOK * fx.y;
    fc0[r] = fmaf(K2E, fx.x * fx.x + fx.y * fx.y, -LOG2S);
  }
  // g-phase: wave w owns 4 cols [blk*32 + w*4, +4); lane scans 32 rows
  const int gcolb = (blk << 5) + (w << 2);
  float gk0[4], gk1[4], gc0[4];
#pragma unroll
  for (int c = 0; c < 4; ++c) {
    float2 gy = pos2[gcolb + c];
    gk0[c] = TWOK * gy.x;
    gk1[c] = TWOK * gy.y;
    gc0[c] = fmaf(K2E, gy.x * gy.x + gy.y * gy.y, logb2[gcolb + c]);
  }

  int target = 0;

  for (int it = 0; it < ITERS; ++it) {
    // ---- stage qy = G2 - K*y2 (4KB agent-scope reads)
#pragma unroll
    for (int k = 0; k < 2; ++k) {
      int e = t + (k << 9);
      shf[e + (e >> 7)].z = fmaf(-K2E, yr2[k], coh_load(&G2b[e]));
    }
    __syncthreads();
    // ---- f-compute: online chunked LSE, 8 rows in regs per lane
    {
      float m[8], s[8];
#pragma unroll
      for (int r = 0; r < 8; ++r) { m[r] = -3.4e38f; s[r] = 0.0f; }
#pragma unroll
      for (int ch = 0; ch < 2; ++ch) {
        float4 a[8];
#pragma unroll
        for (int i = 0; i < 8; ++i) {
          int e = (((ch << 3) + i) << 6) + lane;  // conflict-free b128
          a[i] = shf[e + (e >> 7)];
        }
#pragma unroll
        for (int r = 0; r < 8; ++r) {
          float u0 = fmaf(fk0[r], a[0].x, fmaf(fk1[r], a[0].y, a[0].z));
          float u1 = fmaf(fk0[r], a[1].x, fmaf(fk1[r], a[1].y, a[1].z));
          float u2 = fmaf(fk0[r], a[2].x, fmaf(fk1[r], a[2].y, a[2].z));
          float u3 = fmaf(fk0[r], a[3].x, fmaf(fk1[r], a[3].y, a[3].z));
          float u4 = fmaf(fk0[r], a[4].x, fmaf(fk1[r], a[4].y, a[4].z));
          float u5 = fmaf(fk0[r], a[5].x, fmaf(fk1[r], a[5].y, a[5].z));
          float u6 = fmaf(fk0[r], a[6].x, fmaf(fk1[r], a[6].y, a[6].z));
          float u7 = fmaf(fk0[r], a[7].x, fmaf(fk1[r], a[7].y, a[7].z));
          float cm = fmaxf(fmaxf(fmaxf(u0, u1), fmaxf(u2, u3)),
                           fmaxf(fmaxf(u4, u5), fmaxf(u6, u7)));
          float mn = fmaxf(m[r], cm);
          float sc = fexp2(m[r] - mn);
          float sum = ((fexp2(u0 - mn) + fexp2(u1 - mn)) +
                       (fexp2(u2 - mn) + fexp2(u3 - mn))) +
                      ((fexp2(u4 - mn) + fexp2(u5 - mn)) +
                       (fexp2(u6 - mn) + fexp2(u7 - mn)));
          s[r] = fmaf(s[r], sc, sum);
          m[r] = mn;
        }
      }
      // lane merge: max-butterfly, one rescale, sum-butterfly
#pragma unroll
      for (int r = 0; r < 8; ++r) {
        float M = m[r];
#pragma unroll
        for (int off = 1; off <= 32; off <<= 1)
          M = fmaxf(M, __shfl_xor(M, off, 64));
        float sr = s[r] * fexp2(m[r] - M);
#pragma unroll
        for (int off = 1; off <= 32; off <<= 1) sr += __shfl_xor(sr, off, 64);
        if (lane == 0)
          coh_store(&F2g[frowb + r], fc0[r] - M - flog2(sr));
      }
    }
    target += BLK_PER_BATCH;
    batch_barrier(mycnt, target);

    // ---- stage qx = F2 - K*x2 (8KB agent-scope reads)
#pragma unroll
    for (int k = 0; k < 4; ++k) {
      int e = t + (k << 9);
      shg[e + (e >> 7)].z = fmaf(-K2E, xr2[k], coh_load(&F2b[e]));
    }
    __syncthreads();
    // ---- g-compute: online chunked LSE, 4 cols in regs per lane
    {
      float m[4], s[4];
#pragma unroll
      for (int c = 0; c < 4; ++c) { m[c] = -3.4e38f; s[c] = 0.0f; }
#pragma unroll
      for (int ch = 0; ch < 4; ++ch) {
        float4 a[8];
#pragma unroll
        for (int i = 0; i < 8; ++i) {
          int e = (((ch << 3) + i) << 6) + lane;
          a[i] = shg[e + (e >> 7)];
        }
#pragma unroll
        for (int c = 0; c < 4; ++c) {
          float u0 = fmaf(gk0[c], a[0].x, fmaf(gk1[c], a[0].y, a[0].z));
          float u1 = fmaf(gk0[c], a[1].x, fmaf(gk1[c], a[1].y, a[1].z));
          float u2 = fmaf(gk0[c], a[2].x, fmaf(gk1[c], a[2].y, a[2].z));
          float u3 = fmaf(gk0[c], a[3].x, fmaf(gk1[c], a[3].y, a[3].z));
          float u4 = fmaf(gk0[c], a[4].x, fmaf(gk1[c], a[4].y, a[4].z));
          float u5 = fmaf(gk0[c], a[5].x, fmaf(gk1[c], a[5].y, a[5].z));
          float u6 = fmaf(gk0[c], a[6].x, fmaf(gk1[c], a[6].y, a[6].z));
          float u7 = fmaf(gk0[c], a[7].x, fmaf(gk1[c], a[7].y, a[7].z));
          float cm = fmaxf(fmaxf(fmaxf(u0, u1), fmaxf(u2, u3)),
                           fmaxf(fmaxf(u4, u5), fmaxf(u6, u7)));
          float mn = fmaxf(m[c], cm);
          float sc = fexp2(m[c] - mn);
          float sum = ((fexp2(u0 - mn) + fexp2(u1 - mn)) +
                       (fexp2(u2 - mn) + fexp2(u3 - mn))) +
                      ((fexp2(u4 - mn) + fexp2(u5 - mn)) +
                       (fexp2(u6 - mn) + fexp2(u7 - mn)));
          s[c] = fmaf(s[c], sc, sum);
          m[c] = mn;
        }
      }
#pragma unroll
      for (int c = 0; c < 4; ++c) {
        float M = m[c];
#pragma unroll
        for (int off = 1; off <= 32; off <<= 1)
          M = fmaxf(M, __shfl_xor(M, off, 64));
        float sr = s[c] * fexp2(m[c] - M);
#pragma unroll
        for (int off = 1; off <= 32; off <<= 1) sr += __shfl_xor(sr, off, 64);
        if (lane == 0)
          coh_store(&G2g[gcolb + c], gc0[c] - M - flog2(sr));
      }
    }
    target += BLK_PER_BATCH;
    batch_barrier(mycnt, target);
  }

  // ---- fused final: restage qy with final G2, rowsum over own 64 rows
  if (t == 0) spart = 0.0f;
#pragma unroll
  for (int k = 0; k < 2; ++k) {
    int e = t + (k << 9);
    shf[e + (e >> 7)].z = fmaf(-K2E, yr2[k], coh_load(&G2b[e]));
  }
  __syncthreads();
  float acc = 0.0f;
#pragma unroll
  for (int rr = 0; rr < 8; ++rr) {
    int row = frowb + rr;
    float2 x = preds2[row];
    float x2 = x.x * x.x + x.y * x.y;
    float qx = fmaf(-K2E, x2, coh_load(&F2g[row]));
#pragma unroll
    for (int i = 0; i < 16; ++i) {
      int p = (i << 6) + lane;
      float4 a = shf[p + (p >> 7)];
      float y2 = fmaf(a.x, a.x, a.y * a.y);
      float tt = fmaf(x.y, a.y, x.x * a.x);
      float c = fmaxf(x2 + y2 - 2.0f * tt, 0.0f);  // clamped cost
      float v2 = fmaf(TWOK, tt, a.z + qx);         // -K*C' + F2 + G2 (base-2)
      acc = fmaf(fexp2(v2), c, acc);               // c==0 kills C'<0 case
    }
  }
#pragma unroll
  for (int off = 32; off; off >>= 1) acc += __shfl_xor(acc, off, 64);
  if (lane == 0) atomicAdd(&spart, acc);
  __syncthreads();
  if (t == 0) atomicAdd(out, spart * (1.0f / (float)BB));
}

extern "C" void kernel_launch(void* const* d_in, const int* in_sizes, int n_in,
                              void* d_out, int out_size, void* d_ws,
                              size_t ws_size, hipStream_t stream) {
  const float* preds = (const float*)d_in[0];  // [B,S,2]
  const int* labels = (const int*)d_in[1];     // [B,S]
  const float* pos = (const float*)d_in[2];    // [B,P,2]
  float* out = (float*)d_out;
  char* ws = (char*)d_ws;
  float* G2 = (float*)(ws);
  float* F2 = (float*)(ws + 32768);
  float* logb2 = (float*)(ws + 98304);
  int* cnt = (int*)(ws + 131072);

  hipLaunchKernelGGL(setup_kernel, dim3(BB), dim3(1024), 0, stream, labels, G2,
                     logb2, cnt, out);
  hipLaunchKernelGGL(sinkhorn_persist, dim3(NBLK), dim3(512), 0, stream,
                     preds, pos, logb2, F2, G2, cnt, out);
}

// Round 7
// 611.042 us; speedup vs baseline: 6.5232x; 1.2756x over previous
//
#include <hip/hip_runtime.h>
#include <math.h>

// Sinkhorn loss, B=8, S=2048, P=1024, D=2, eps=0.01, 50 iters.
// PERSISTENT-KERNEL v7 — 4 waves/SIMD + RMW-free store/poll barrier +
// coalesced potential writes.
// R6 evidence: VALUBusy scales ~linearly with waves (17%@1, 48%@2) => still
// latency-bound, go to 4 waves/SIMD (1024 thr, plain launch_bounds — the
// ",4" variant forced VGPR=64+spills in R5). WRITE_SIZE 39MB identical in
// R4/R6 => it's uncached 4B coh_stores (64B txn each) + barrier RMWs, not
// spills: coalesce writes (lane r holds value r, lanes 0..3 store together)
// and replace the 32-serialized-fetch_add convoy with store+poll: each block
// STOREs its phase to its own slot (parallel), wave0 polls 32 slots with one
// lane each + __all. All cross-block data still relaxed agent-scope (proven
// R6, absmax 0.0).
// Base-2 scaled potentials: F2 = f/(eps*ln2), G2 = g/(eps*ln2), K = 100*log2(e)
//   f elem: u = 2K*x.y + (G2[p] - K*y2[p]);  F2 = (K*x2 - log2 S) - LSE2(u)
//   g elem: u = 2K*x.y + (F2[s] - K*x2[s]);  G2 = (K*y2 + logb2) - LSE2(u)

#define BB 8
#define SS 2048
#define PP 1024
#define NEG_INF -1e9f
#define LOG2S 11.0f
#define ITERS 50
#define K2E 144.269504088896f   /* 100*log2(e) */
#define TWOK 288.539008177792f  /* 200*log2(e) */
#define NBLK 256
#define NTHR 1024

__device__ __forceinline__ float fexp2(float x) {
  return __builtin_amdgcn_exp2f(x);
}
__device__ __forceinline__ float flog2(float x) {
  return __builtin_amdgcn_logf(x);
}

// agent-scope coherent (cache-bypassing) accessors, RELAXED only (proven R6)
__device__ __forceinline__ float coh_load(const float* p) {
  return __hip_atomic_load((float*)p, __ATOMIC_RELAXED, __HIP_MEMORY_SCOPE_AGENT);
}
__device__ __forceinline__ void coh_store(float* p, float v) {
  __hip_atomic_store(p, v, __ATOMIC_RELAXED, __HIP_MEMORY_SCOPE_AGENT);
}
__device__ __forceinline__ int coh_loadi(const int* p) {
  return __hip_atomic_load((int*)p, __ATOMIC_RELAXED, __HIP_MEMORY_SCOPE_AGENT);
}
__device__ __forceinline__ void coh_storei(int* p, int v) {
  __hip_atomic_store(p, v, __ATOMIC_RELAXED, __HIP_MEMORY_SCOPE_AGENT);
}

// 32-block per-batch barrier, RMW-free. slots = this batch's 32 ints.
// __syncthreads() drains every wave's stores (vmcnt0) before the slot store;
// wave 0 polls all 32 slots in parallel (lane j watches slot j).
__device__ __forceinline__ void batch_barrier(int* slots, int sub, int phase,
                                              int w, int lane) {
  __syncthreads();
  asm volatile("" ::: "memory");
  if (threadIdx.x == 0) coh_storei(&slots[sub], phase);
  if (w == 0) {
    for (;;) {
      int v = (lane < 32) ? coh_loadi(&slots[lane]) : 0x7fffffff;
      if (__all(v >= phase)) break;
      __builtin_amdgcn_s_sleep(1);
    }
  }
  asm volatile("" ::: "memory");
  __syncthreads();
}

// ws layout (bytes):
//   G2    : [0,      32768)   B*P float
//   F2    : [32768,  98304)   B*S float
//   logb2 : [98304, 131072)   B*P float
//   slots : [131072, 132096)  8 batches x 32 ints (phase slots)

__global__ __launch_bounds__(1024) void setup_kernel(
    const int* __restrict__ labels, float* __restrict__ G2,
    float* __restrict__ logb2, int* __restrict__ slots,
    float* __restrict__ out) {
  __shared__ int c[PP];
  int b = blockIdx.x;
  int t = threadIdx.x;  // 1024 threads
  c[t] = 0;
  __syncthreads();
  atomicAdd(&c[labels[b * SS + t] & (PP - 1)], 1);
  atomicAdd(&c[labels[b * SS + PP + t] & (PP - 1)], 1);
  __syncthreads();
  int cc = c[t];
  logb2[b * PP + t] = (cc > 0) ? (flog2((float)cc) - LOG2S) : NEG_INF;
  G2[b * PP + t] = 0.0f;
  if (t < 32) slots[(b << 5) + t] = 0;
  if (t == 0 && b == 0) out[0] = 0.0f;
}

__global__ __launch_bounds__(1024) void sinkhorn_persist(
    const float* __restrict__ preds, const float* __restrict__ pos,
    const float* __restrict__ logb2, float* __restrict__ F2g,
    float* __restrict__ G2g, int* __restrict__ slots,
    float* __restrict__ out) {
  __shared__ float4 shf[1032];  // (y0, y1, qy = G2 - K*y2, pad), +16B pad /128
  __shared__ float4 shg[2064];  // (x0, x1, qx = F2 - K*x2, pad), +16B pad /128
  __shared__ float spart;
  const int t = threadIdx.x;    // 1024 threads, 16 waves
  const int blk = blockIdx.x;   // 256 blocks = 1/CU exactly
  const int bb = blk >> 5;      // 32 blocks per batch
  const int sub = blk & 31;
  int* myslots = slots + (bb << 5);
  const float2* pos2 = (const float2*)pos;
  const float2* preds2 = (const float2*)preds;
  float* G2b = G2g + (bb << 10);
  float* F2b = F2g + (bb << 11);

  // ---- persistent init: x/y constants into LDS + K-scaled norms in regs
  float yr2, xr2[2];
  {
    float2 y = pos2[(bb << 10) + t];
    yr2 = y.x * y.x + y.y * y.y;
    shf[t + (t >> 7)] = make_float4(y.x, y.y, 0.0f, 0.0f);
  }
#pragma unroll
  for (int k = 0; k < 2; ++k) {
    int e = t + (k << 10);
    float2 x = preds2[(bb << 11) + e];
    xr2[k] = x.x * x.x + x.y * x.y;
    shg[e + (e >> 7)] = make_float4(x.x, x.y, 0.0f, 0.0f);
  }

  const int w = t >> 6, lane = t & 63;
  // f-phase: wave w owns 4 rows [blk*64 + w*4, +4); lane scans 16 cols
  const int frowb = (blk << 6) + (w << 2);
  float fk0[4], fk1[4], fc0[4];
#pragma unroll
  for (int r = 0; r < 4; ++r) {
    float2 fx = preds2[frowb + r];  // wave-uniform broadcast load
    fk0[r] = TWOK * fx.x;
    fk1[r] = TWOK * fx.y;
    fc0[r] = fmaf(K2E, fx.x * fx.x + fx.y * fx.y, -LOG2S);
  }
  // g-phase: wave w owns 2 cols [blk*32 + w*2, +2); lane scans 32 rows
  const int gcolb = (blk << 5) + (w << 1);
  float gk0[2], gk1[2], gc0[2];
#pragma unroll
  for (int c = 0; c < 2; ++c) {
    float2 gy = pos2[gcolb + c];
    gk0[c] = TWOK * gy.x;
    gk1[c] = TWOK * gy.y;
    gc0[c] = fmaf(K2E, gy.x * gy.x + gy.y * gy.y, logb2[gcolb + c]);
  }

  for (int it = 0; it < ITERS; ++it) {
    // ---- stage qy = G2 - K*y2 (4KB agent-scope reads)
    shf[t + (t >> 7)].z = fmaf(-K2E, yr2, coh_load(&G2b[t]));
    __syncthreads();
    // ---- f-compute: online chunked LSE, 4 rows in regs per lane
    {
      float m[4], s[4];
#pragma unroll
      for (int r = 0; r < 4; ++r) { m[r] = -3.4e38f; s[r] = 0.0f; }
#pragma unroll
      for (int ch = 0; ch < 2; ++ch) {
        float4 a[8];
#pragma unroll
        for (int i = 0; i < 8; ++i) {
          int e = (((ch << 3) + i) << 6) + lane;  // conflict-free b128
          a[i] = shf[e + (e >> 7)];
        }
#pragma unroll
        for (int r = 0; r < 4; ++r) {
          float u0 = fmaf(fk0[r], a[0].x, fmaf(fk1[r], a[0].y, a[0].z));
          float u1 = fmaf(fk0[r], a[1].x, fmaf(fk1[r], a[1].y, a[1].z));
          float u2 = fmaf(fk0[r], a[2].x, fmaf(fk1[r], a[2].y, a[2].z));
          float u3 = fmaf(fk0[r], a[3].x, fmaf(fk1[r], a[3].y, a[3].z));
          float u4 = fmaf(fk0[r], a[4].x, fmaf(fk1[r], a[4].y, a[4].z));
          float u5 = fmaf(fk0[r], a[5].x, fmaf(fk1[r], a[5].y, a[5].z));
          float u6 = fmaf(fk0[r], a[6].x, fmaf(fk1[r], a[6].y, a[6].z));
          float u7 = fmaf(fk0[r], a[7].x, fmaf(fk1[r], a[7].y, a[7].z));
          float cm = fmaxf(fmaxf(fmaxf(u0, u1), fmaxf(u2, u3)),
                           fmaxf(fmaxf(u4, u5), fmaxf(u6, u7)));
          float mn = fmaxf(m[r], cm);
          float sc = fexp2(m[r] - mn);
          float sum = ((fexp2(u0 - mn) + fexp2(u1 - mn)) +
                       (fexp2(u2 - mn) + fexp2(u3 - mn))) +
                      ((fexp2(u4 - mn) + fexp2(u5 - mn)) +
                       (fexp2(u6 - mn) + fexp2(u7 - mn)));
          s[r] = fmaf(s[r], sc, sum);
          m[r] = mn;
        }
      }
      // lane merge + coalesced store: lane r keeps value r, lanes 0..3 store
      float fout = 0.0f;
#pragma unroll
      for (int r = 0; r < 4; ++r) {
        float M = m[r];
#pragma unroll
        for (int off = 1; off <= 32; off <<= 1)
          M = fmaxf(M, __shfl_xor(M, off, 64));
        float sr = s[r] * fexp2(m[r] - M);
#pragma unroll
        for (int off = 1; off <= 32; off <<= 1) sr += __shfl_xor(sr, off, 64);
        float v = fc0[r] - M - flog2(sr);
        if (lane == r) fout = v;
      }
      if (lane < 4) coh_store(&F2g[frowb + lane], fout);
    }
    batch_barrier(myslots, sub, 2 * it + 1, w, lane);

    // ---- stage qx = F2 - K*x2 (8KB agent-scope reads)
#pragma unroll
    for (int k = 0; k < 2; ++k) {
      int e = t + (k << 10);
      shg[e + (e >> 7)].z = fmaf(-K2E, xr2[k], coh_load(&F2b[e]));
    }
    __syncthreads();
    // ---- g-compute: online chunked LSE, 2 cols in regs per lane
    {
      float m[2], s[2];
#pragma unroll
      for (int c = 0; c < 2; ++c) { m[c] = -3.4e38f; s[c] = 0.0f; }
#pragma unroll
      for (int ch = 0; ch < 4; ++ch) {
        float4 a[8];
#pragma unroll
        for (int i = 0; i < 8; ++i) {
          int e = (((ch << 3) + i) << 6) + lane;
          a[i] = shg[e + (e >> 7)];
        }
#pragma unroll
        for (int c = 0; c < 2; ++c) {
          float u0 = fmaf(gk0[c], a[0].x, fmaf(gk1[c], a[0].y, a[0].z));
          float u1 = fmaf(gk0[c], a[1].x, fmaf(gk1[c], a[1].y, a[1].z));
          float u2 = fmaf(gk0[c], a[2].x, fmaf(gk1[c], a[2].y, a[2].z));
          float u3 = fmaf(gk0[c], a[3].x, fmaf(gk1[c], a[3].y, a[3].z));
          float u4 = fmaf(gk0[c], a[4].x, fmaf(gk1[c], a[4].y, a[4].z));
          float u5 = fmaf(gk0[c], a[5].x, fmaf(gk1[c], a[5].y, a[5].z));
          float u6 = fmaf(gk0[c], a[6].x, fmaf(gk1[c], a[6].y, a[6].z));
          float u7 = fmaf(gk0[c], a[7].x, fmaf(gk1[c], a[7].y, a[7].z));
          float cm = fmaxf(fmaxf(fmaxf(u0, u1), fmaxf(u2, u3)),
                           fmaxf(fmaxf(u4, u5), fmaxf(u6, u7)));
          float mn = fmaxf(m[c], cm);
          float sc = fexp2(m[c] - mn);
          float sum = ((fexp2(u0 - mn) + fexp2(u1 - mn)) +
                       (fexp2(u2 - mn) + fexp2(u3 - mn))) +
                      ((fexp2(u4 - mn) + fexp2(u5 - mn)) +
                       (fexp2(u6 - mn) + fexp2(u7 - mn)));
          s[c] = fmaf(s[c], sc, sum);
          m[c] = mn;
        }
      }
      float gout = 0.0f;
#pragma unroll
      for (int c = 0; c < 2; ++c) {
        float M = m[c];
#pragma unroll
        for (int off = 1; off <= 32; off <<= 1)
          M = fmaxf(M, __shfl_xor(M, off, 64));
        float sr = s[c] * fexp2(m[c] - M);
#pragma unroll
        for (int off = 1; off <= 32; off <<= 1) sr += __shfl_xor(sr, off, 64);
        float v = gc0[c] - M - flog2(sr);
        if (lane == c) gout = v;
      }
      if (lane < 2) coh_store(&G2g[gcolb + lane], gout);
    }
    batch_barrier(myslots, sub, 2 * it + 2, w, lane);
  }

  // ---- fused final: restage qy with final G2, rowsum over own 64 rows
  if (t == 0) spart = 0.0f;
  shf[t + (t >> 7)].z = fmaf(-K2E, yr2, coh_load(&G2b[t]));
  __syncthreads();
  float acc = 0.0f;
#pragma unroll
  for (int rr = 0; rr < 4; ++rr) {
    int row = frowb + rr;
    float2 x = preds2[row];
    float x2 = x.x * x.x + x.y * x.y;
    float qx = fmaf(-K2E, x2, coh_load(&F2g[row]));
#pragma unroll
    for (int i = 0; i < 16; ++i) {
      int p = (i << 6) + lane;
      float4 a = shf[p + (p >> 7)];
      float y2 = fmaf(a.x, a.x, a.y * a.y);
      float tt = fmaf(x.y, a.y, x.x * a.x);
      float c = fmaxf(x2 + y2 - 2.0f * tt, 0.0f);  // clamped cost
      float v2 = fmaf(TWOK, tt, a.z + qx);         // -K*C' + F2 + G2 (base-2)
      acc = fmaf(fexp2(v2), c, acc);               // c==0 kills C'<0 case
    }
  }
#pragma unroll
  for (int off = 32; off; off >>= 1) acc += __shfl_xor(acc, off, 64);
  if (lane == 0) atomicAdd(&spart, acc);
  __syncthreads();
  if (t == 0) atomicAdd(out, spart * (1.0f / (float)BB));
}

extern "C" void kernel_launch(void* const* d_in, const int* in_sizes, int n_in,
                              void* d_out, int out_size, void* d_ws,
                              size_t ws_size, hipStream_t stream) {
  const float* preds = (const float*)d_in[0];  // [B,S,2]
  const int* labels = (const int*)d_in[1];     // [B,S]
  const float* pos = (const float*)d_in[2];    // [B,P,2]
  float* out = (float*)d_out;
  char* ws = (char*)d_ws;
  float* G2 = (float*)(ws);
  float* F2 = (float*)(ws + 32768);
  float* logb2 = (float*)(ws + 98304);
  int* slots = (int*)(ws + 131072);

  hipLaunchKernelGGL(setup_kernel, dim3(BB), dim3(1024), 0, stream, labels, G2,
                     logb2, slots, out);
  hipLaunchKernelGGL(sinkhorn_persist, dim3(NBLK), dim3(NTHR), 0, stream,
                     preds, pos, logb2, F2, G2, slots, out);
}